// Round 3
// baseline (515.675 us; speedup 1.0000x reference)
//
#include <hip/hip_runtime.h>

typedef __attribute__((ext_vector_type(8))) short short8;
typedef __attribute__((ext_vector_type(4))) float f32x4;
typedef __attribute__((ext_vector_type(4))) int i32x4;

#define LOG2E 1.44269504f

__device__ __forceinline__ short f2bf(float f) {
  unsigned u = __builtin_bit_cast(unsigned, f);
  u += 0x7fffu + ((u >> 16) & 1u);   // round-to-nearest-even
  return (short)(u >> 16);
}

// ---------------- kernel A: w1 = W@a1, w2 = W@a2 (fp32) ----------------
__global__ void gat_wvec(const float* __restrict__ W, const float* __restrict__ a1,
                         const float* __restrict__ a2, float* __restrict__ w1,
                         float* __restrict__ w2) {
  __shared__ float a1f[256], a2f[256];
  const int tid = threadIdx.x;
  a1f[tid] = a1[tid];
  a2f[tid] = a2[tid];
  __syncthreads();
  float s1 = 0.f, s2 = 0.f;
  const float4* wr = (const float4*)(W + (size_t)tid * 256);
  for (int d0 = 0; d0 < 64; ++d0) {
    float4 v = wr[d0];
    s1 += v.x * a1f[d0 * 4] + v.y * a1f[d0 * 4 + 1] + v.z * a1f[d0 * 4 + 2] + v.w * a1f[d0 * 4 + 3];
    s2 += v.x * a2f[d0 * 4] + v.y * a2f[d0 * 4 + 1] + v.z * a2f[d0 * 4 + 2] + v.w * a2f[d0 * 4 + 3];
  }
  w1[tid] = s1;
  w2[tid] = s2;
}

// ------------- f32 -> bf16 convert + transpose: dst[b][c][r] = bf16(src[b][r][c]) -------------
__global__ void convT(const float* __restrict__ src, short* __restrict__ dst,
                      int R, int C) {
  __shared__ short T[64][72];
  const int tid = threadIdx.x;
  const int bc = blockIdx.x, br = blockIdx.y, bb = blockIdx.z;
  const float* s = src + (size_t)bb * R * C;
  short* d = dst + (size_t)bb * R * C;
  const int rr = tid >> 2, cc = (tid & 3) << 4;
  const float4* sp = (const float4*)(s + (size_t)(br * 64 + rr) * C + bc * 64 + cc);
  alignas(16) short v[16];
#pragma unroll
  for (int g = 0; g < 4; ++g) {
    float4 x = sp[g];
    v[g * 4 + 0] = f2bf(x.x);
    v[g * 4 + 1] = f2bf(x.y);
    v[g * 4 + 2] = f2bf(x.z);
    v[g * 4 + 3] = f2bf(x.w);
  }
  *(short8*)&T[rr][cc] = *(short8*)&v[0];
  *(short8*)&T[rr][cc + 8] = *(short8*)&v[8];
  __syncthreads();
#pragma unroll
  for (int j = 0; j < 16; ++j) v[j] = T[cc + j][rr];
  short8* dp = (short8*)(d + (size_t)(bc * 64 + rr) * R + br * 64 + cc);
  dp[0] = *(short8*)&v[0];
  dp[1] = *(short8*)&v[8];
}

// ---------------- kernel B: Ax/Ay (one wave per row, f32 feat) ----------------
__global__ void gat_axay(const float* __restrict__ feat, const float* __restrict__ w1,
                         const float* __restrict__ w2, float* __restrict__ Ax,
                         float* __restrict__ Ay) {
  const int lane = threadIdx.x & 63;
  const int row = blockIdx.x * 4 + (threadIdx.x >> 6);
  float4 fv = *(const float4*)(feat + (size_t)row * 256 + lane * 4);
  const float4 w1v = *(const float4*)(w1 + lane * 4);
  const float4 w2v = *(const float4*)(w2 + lane * 4);
  float s1 = fv.x * w1v.x + fv.y * w1v.y + fv.z * w1v.z + fv.w * w1v.w;
  float s2 = fv.x * w2v.x + fv.y * w2v.y + fv.z * w2v.z + fv.w * w2v.w;
#pragma unroll
  for (int off = 32; off >= 1; off >>= 1) {
    s1 += __shfl_xor(s1, off);
    s2 += __shfl_xor(s2, off);
  }
  if (lane == 0) { Ax[row] = s1; Ay[row] = s2; }
}

// ---------------- kernel B2: per-batch max of Ax ----------------
__global__ void gat_max(const float* __restrict__ Ax, float* __restrict__ Mb) {
  __shared__ float red[256];
  const int b = blockIdx.x, tid = threadIdx.x;
  float m = -3.4e38f;
  for (int i = tid; i < 4096; i += 256) m = fmaxf(m, Ax[b * 4096 + i]);
  red[tid] = m;
  __syncthreads();
  for (int s = 128; s > 0; s >>= 1) {
    if (tid < s) red[tid] = fmaxf(red[tid], red[tid + s]);
    __syncthreads();
  }
  if (tid == 0) Mb[b] = red[0];
}

// -------- kernel C: fully fused  softmax(mask(lrelu(rank1)))@feat @W +ELU --------
// grid 512 = 2 blocks/CU; XCD-swizzled: xcd=blk&7 -> batch=xcd>>1 so featT[b]
// (2 MB) stays resident in that XCD's 4 MB L2. Block = 256 thr = 4 waves; block
// owns a 32-row i-tile and the FULL j-range; wave owns 64 of the 256 D-cols.
__global__ __launch_bounds__(256, 2) void gat_attn(
    const short* __restrict__ featT,  // [4][256][4096] bf16
    const int* __restrict__ adj,      // [4][4096][4096]
    const float* __restrict__ Ax, const float* __restrict__ Ay,
    const float* __restrict__ Mb,
    const short* __restrict__ WT,     // [256][256] bf16 (W^T)
    float* __restrict__ out)          // [4][4096][256] f32
{
  __shared__ short Pbuf[2][32][72];   // 9,216 B; row stride 144 B = 9x16 (b128-aligned, bank-uniform)
  __shared__ short hbuf[32 * 264];    // 16,896 B; stride 528 B = 33x16
  __shared__ float linv_s[32];

  const int tid = threadIdx.x;
  const int blk = blockIdx.x;
  const int x = blk & 7;
  const int b = x >> 1;                       // XCD-pinned batch
  const int it = ((blk >> 3) << 1) | (x & 1); // 0..127
  const int i0 = it << 5;

  const int r = tid >> 3;            // local row 0..31
  const int c0 = (tid & 7) << 3;     // col base, 8 cols/thread

  const float ay = Ay[b * 4096 + i0 + r];
  float mr = ay + Mb[b];
  mr = mr > 0.f ? mr : 0.2f * mr;    // uniform upper bound on row scores

  const int lane = tid & 63;
  const int w = tid >> 6;
  const int n0 = w << 6;
  const int l15 = lane & 15;
  const int q = lane >> 4;

  f32x4 acc[2][4];
#pragma unroll
  for (int i = 0; i < 2; ++i)
#pragma unroll
    for (int j = 0; j < 4; ++j) acc[i][j] = (f32x4){0.f, 0.f, 0.f, 0.f};

  float lsum = 0.f;

  const i32x4* adjp = (const i32x4*)(adj + ((size_t)(b * 4096 + i0 + r)) * 4096 + c0);
  const float4* axp = (const float4*)(Ax + b * 4096 + c0);
  const short* ftb = featT + ((size_t)(b * 256 + n0 + l15)) * 4096 + q * 8;

  i32x4 adv[2];
  float4 axv[2];
  adv[0] = __builtin_nontemporal_load(adjp);
  adv[1] = __builtin_nontemporal_load(adjp + 1);
  axv[0] = axp[0];
  axv[1] = axp[1];

  for (int jc = 0; jc < 64; ++jc) {
    // ---- phase 1: P tile (exp of masked lrelu scores), bf16 into LDS ----
    alignas(16) short pk[8];
#pragma unroll
    for (int g = 0; g < 2; ++g) {
      const float* af = (const float*)&axv[g];
#pragma unroll
      for (int u = 0; u < 4; ++u) {
        float lg = af[u] + ay;
        float e = lg > 0.f ? lg : 0.2f * lg;
        e = adv[g][u] > 0 ? e : -9e15f;
        float p = __builtin_amdgcn_exp2f((e - mr) * LOG2E);
        lsum += p;
        pk[g * 4 + u] = f2bf(p);
      }
    }
    *(short8*)&Pbuf[jc & 1][r][c0] = *(short8*)pk;
    __syncthreads();

    // prefetch next chunk (in flight across MFMA phase; consumed before next barrier)
    if (jc < 63) {
      adv[0] = __builtin_nontemporal_load(adjp + (jc + 1) * 16);
      adv[1] = __builtin_nontemporal_load(adjp + (jc + 1) * 16 + 1);
      axv[0] = axp[(jc + 1) * 16];
      axv[1] = axp[(jc + 1) * 16 + 1];
    }

    // ---- phase 2: MFMA  acc += P(32x64) * feat-slice(64 x 64cols) ----
    const int j0 = jc << 6;
#pragma unroll
    for (int k0 = 0; k0 < 64; k0 += 32) {
      short8 afr0 = *(const short8*)&Pbuf[jc & 1][l15][k0 + q * 8];
      short8 afr1 = *(const short8*)&Pbuf[jc & 1][16 + l15][k0 + q * 8];
#pragma unroll
      for (int ct = 0; ct < 4; ++ct) {
        short8 bfr = *(const short8*)(ftb + (size_t)ct * 16 * 4096 + j0 + k0);
        acc[0][ct] = __builtin_amdgcn_mfma_f32_16x16x32_bf16(afr0, bfr, acc[0][ct], 0, 0, 0);
        acc[1][ct] = __builtin_amdgcn_mfma_f32_16x16x32_bf16(afr1, bfr, acc[1][ct], 0, 0, 0);
      }
    }
  }

  // ---- row sums: 8 threads per row (lanes adjacent) ----
  float s = lsum;
  s += __shfl_xor(s, 1);
  s += __shfl_xor(s, 2);
  s += __shfl_xor(s, 4);
  if ((tid & 7) == 0) linv_s[r] = s > 0.f ? 1.f / s : 0.f;
  __syncthreads();

  // ---- normalize h' and round-trip C-layout -> A-layout through LDS ----
#pragma unroll
  for (int rt = 0; rt < 2; ++rt)
#pragma unroll
    for (int reg = 0; reg < 4; ++reg) {
      int lr = rt * 16 + q * 4 + reg;       // C/D layout: row = quad*4 + reg
      float li = linv_s[lr];
#pragma unroll
      for (int ct = 0; ct < 4; ++ct)
        hbuf[lr * 264 + n0 + ct * 16 + l15] = f2bf(acc[rt][ct][reg] * li);
    }
  __syncthreads();

  // ---- epilogue GEMM: (32x256) @ W -> 32x256, ELU, store ----
#pragma unroll
  for (int i = 0; i < 2; ++i)
#pragma unroll
    for (int j = 0; j < 4; ++j) acc[i][j] = (f32x4){0.f, 0.f, 0.f, 0.f};

#pragma unroll 2
  for (int k0 = 0; k0 < 256; k0 += 32) {
    short8 afr0 = *(const short8*)&hbuf[l15 * 264 + k0 + q * 8];
    short8 afr1 = *(const short8*)&hbuf[(16 + l15) * 264 + k0 + q * 8];
#pragma unroll
    for (int ct = 0; ct < 4; ++ct) {
      short8 bfr = *(const short8*)(WT + (size_t)(n0 + ct * 16 + l15) * 256 + k0 + q * 8);
      acc[0][ct] = __builtin_amdgcn_mfma_f32_16x16x32_bf16(afr0, bfr, acc[0][ct], 0, 0, 0);
      acc[1][ct] = __builtin_amdgcn_mfma_f32_16x16x32_bf16(afr1, bfr, acc[1][ct], 0, 0, 0);
    }
  }

#pragma unroll
  for (int rt = 0; rt < 2; ++rt)
#pragma unroll
    for (int reg = 0; reg < 4; ++reg) {
      int row = i0 + rt * 16 + q * 4 + reg;
      float* orow = out + ((size_t)(b * 4096 + row)) * 256 + n0 + l15;
#pragma unroll
      for (int ct = 0; ct < 4; ++ct) {
        float v = acc[rt][ct][reg];
        float o = v > 0.f ? v : (__builtin_amdgcn_exp2f(v * LOG2E) - 1.f);
        __builtin_nontemporal_store(o, orow + ct * 16);
      }
    }
}

extern "C" void kernel_launch(void* const* d_in, const int* in_sizes, int n_in,
                              void* d_out, int out_size, void* d_ws, size_t ws_size,
                              hipStream_t stream) {
  (void)in_sizes; (void)n_in; (void)out_size; (void)ws_size;
  const float* feat = (const float*)d_in[0];
  const int* adj = (const int*)d_in[1];
  const float* W = (const float*)d_in[2];
  const float* a1 = (const float*)d_in[3];
  const float* a2 = (const float*)d_in[4];
  float* out = (float*)d_out;

  char* ws = (char*)d_ws;
  short* featT = (short*)ws;                   // 8,388,608 B  [4][256][4096] bf16
  short* WT    = (short*)(ws + 8388608);       // 131,072 B    [256][256] bf16
  float* w1    = (float*)(ws + 8519680);       // 1 KB
  float* w2    = (float*)(ws + 8520704);       // 1 KB
  float* Ax    = (float*)(ws + 8521728);       // 64 KB
  float* Ay    = (float*)(ws + 8587264);       // 64 KB
  float* Mb    = (float*)(ws + 8652800);       // 16 B

  hipLaunchKernelGGL(gat_wvec, dim3(1), dim3(256), 0, stream, W, a1, a2, w1, w2);
  hipLaunchKernelGGL(convT, dim3(4, 4, 1), dim3(256), 0, stream, W, WT, 256, 256);
  hipLaunchKernelGGL(convT, dim3(4, 64, 4), dim3(256), 0, stream, feat, featT, 4096, 256);
  hipLaunchKernelGGL(gat_axay, dim3(4096), dim3(256), 0, stream, feat, w1, w2, Ax, Ay);
  hipLaunchKernelGGL(gat_max, dim3(4), dim3(256), 0, stream, Ax, Mb);
  hipLaunchKernelGGL(gat_attn, dim3(512), dim3(256), 0, stream, featT, adj, Ax, Ay, Mb, WT, out);
}